// Round 10
// baseline (41.541 us; speedup 1.0000x reference)
//
#include <hip/hip_runtime.h>

// Overlap-add: y[b, f*256 + c] += x[b, c, f]
// x: [16, 1024, 2048] f32, y: [16, 525056] f32
// WIN/HOP = 4 -> y[b, g*256 + r] = sum_{k=0}^{3} x[b, k*256 + r, g - k]
//
// R10: wave-autonomous pipelines. Each wave owns items of 128 g x 4 r (8 KB),
// DMAs all four k-slabs into its PRIVATE LDS double-buffer and consumes them
// itself -> per-wave vmcnt is exact, NO s_barrier anywhere. 8 decoupled
// streams per CU, each: fill(t+1) [8 DMAs]; vmcnt(10); phase2(t).
// Decode is pure shifts (wid -> b, rsp, tile-group); a wave walks 8-9
// consecutive tiles -> sequential 512B read segments, L2 reuse at window
// boundaries. Phase-2 LDS reads: bank = j%32 = lane%32 -> 2 lanes/bank, free.

constexpr int BATCH   = 16;
constexpr int WIN     = 1024;
constexpr int HOP     = 256;
constexpr int NF      = 2048;                       // frames
constexpr int OUT_LEN = (NF - 1) * HOP + WIN;       // 525056
constexpr int GTOT    = OUT_LEN / HOP;              // 2051
constexpr int FT      = 128;                        // g-values per item
constexpr int RBW     = 4;                          // r-values per item
constexpr int NBLK    = 512;                        // 2 blocks/CU (64 KB LDS)

typedef float f4a __attribute__((ext_vector_type(4), aligned(16)));

__global__ __launch_bounds__(256, 2)
void oadd_kernel(const float* __restrict__ x, float* __restrict__ y) {
    // L[wave][buf][k][rl][j] = x[b, k*256 + rbase+rl, g0 + j - k]
    __shared__ float L[4][2][4][RBW][FT];           // 65536 B

    const int tid = threadIdx.x;
    const int w   = tid >> 6;
    const int l   = tid & 63;

    // wave-global id -> (b, rsp, tile-group), all pow2 shifts
    const int wid = blockIdx.x * 4 + w;             // 0..2047
    const int b   = wid >> 7;                       // 0..15
    const int rsp = (wid >> 1) & 63;                // 0..63
    const int tg  = wid & 1;                        // 0: tiles 0..7, 1: 8..16
    const int T   = tg ? 9 : 8;
    const int rbase = rsp * RBW;

    const float* __restrict__ xb = x + (size_t)b * WIN * NF;
    float* __restrict__ yb = y + (size_t)b * OUT_LEN;

    const int ch = (l & 31) * 4;                    // col chunk within window
    const int rh = l >> 5;                          // row 0/1 within a DMA

    // fill: 8 fire-and-forget 1KB DMAs (4 k-slabs x 2 row-pairs), all by THIS wave
    auto fill = [&](int t, int s) {
        const int tile = tg * 8 + t;
        const bool m2  = (tile == 16);              // last tile: clamped window
        const int g0   = tile * FT;
        #pragma unroll
        for (int k = 0; k < 4; ++k) {
            // m2: window [NF-FT, NF) for all k (remapped in phase2).
            // tile 0, k>0, ch==0: col<0 dips into previous row's tail
            // (row >= 256 so in-bounds garbage; masked in phase2).
            const int col = m2 ? (NF - FT) + ch : g0 + ch - k;
            #pragma unroll
            for (int i = 0; i < 2; ++i) {
                const int row = k * HOP + rbase + i * 2 + rh;
                const float* src = xb + (size_t)row * NF + col;
                __builtin_amdgcn_global_load_lds(
                    (const __attribute__((address_space(1))) unsigned int*)src,
                    (__attribute__((address_space(3))) unsigned int*)&L[w][s][k][i * 2][0],
                    16, 0, 0);
            }
        }
    };

    // phase2: k-sum + transpose-out. 32 ds_read_b32/lane, 2 lanes/bank (free).
    auto phase2 = [&](int t, int s) {
        const int tile = tg * 8 + t;
        const int g0   = tile * FT;
        if (tile == 0) {
            #pragma unroll
            for (int p = 0; p < 2; ++p) {
                const int j = p * 64 + l;
                f4a v;
                #pragma unroll
                for (int m = 0; m < 4; ++m) {
                    float a = L[w][s][0][m][j];
                    if (j >= 1) a += L[w][s][1][m][j];
                    if (j >= 2) a += L[w][s][2][m][j];
                    if (j >= 3) a += L[w][s][3][m][j];
                    v[m] = a;
                }
                *reinterpret_cast<f4a*>(&yb[(size_t)(g0 + j) * HOP + rbase]) = v;
            }
        } else if (tile == 16) {
            // valid g only for j<3; window is [NF-FT,NF): f=g0+j-k -> idx FT-k+j
            if (l < 3) {
                const int j = l;
                f4a v;
                #pragma unroll
                for (int m = 0; m < 4; ++m) {
                    float a = 0.f;
                    #pragma unroll
                    for (int k = 1; k < 4; ++k)
                        if (k > j) a += L[w][s][k][m][FT - k + j];
                    v[m] = a;
                }
                *reinterpret_cast<f4a*>(&yb[(size_t)(g0 + j) * HOP + rbase]) = v;
            }
        } else {
            #pragma unroll
            for (int p = 0; p < 2; ++p) {
                const int j = p * 64 + l;
                f4a v;
                #pragma unroll
                for (int m = 0; m < 4; ++m) {
                    v[m] = (L[w][s][0][m][j] + L[w][s][1][m][j])
                         + (L[w][s][2][m][j] + L[w][s][3][m][j]);
                }
                *reinterpret_cast<f4a*>(&yb[(size_t)(g0 + j) * HOP + rbase]) = v;
            }
        }
    };

    // ---- per-wave 2-deep pipeline, no barriers ----
    fill(0, 0);
    for (int t = 0; t < T; ++t) {
        if (t + 1 < T) fill(t + 1, (t + 1) & 1);
        // counted vmcnt: guarantee item t's 8 DMAs retired while keeping
        // item t+1's DMAs (8) + previous stores (2) in flight.
        if (t == 0)         asm volatile("s_waitcnt vmcnt(8)"  ::: "memory");
        else if (t + 1 < T) asm volatile("s_waitcnt vmcnt(10)" ::: "memory");
        else                asm volatile("s_waitcnt vmcnt(2)"  ::: "memory");
        phase2(t, t & 1);
    }
}

extern "C" void kernel_launch(void* const* d_in, const int* in_sizes, int n_in,
                              void* d_out, int out_size, void* d_ws, size_t ws_size,
                              hipStream_t stream) {
    const float* x = (const float*)d_in[0];
    float* y = (float*)d_out;
    oadd_kernel<<<dim3(NBLK), 256, 0, stream>>>(x, y);
}

// Round 11
// 36.148 us; speedup vs baseline: 1.1492x; 1.1492x over previous
//
#include <hip/hip_runtime.h>

// Overlap-add: y[b, f*256 + c] += x[b, c, f]
// x: [16, 1024, 2048] f32, y: [16, 525056] f32
// WIN/HOP = 4 -> y[b, g*256 + r] = sum_{k=0}^{3} x[b, k*256 + r, g - k]
//
// R11: barrier-free streaming pipeline.
//  - block = (half, b, rsp); walks its tile range SEQUENTIALLY -> each block
//    streams 64 x-rows end-to-end (perfect sequential reads, decode = t++).
//  - wave w owns rows rbase+4w..+4 for ALL k: producer == consumer wave ->
//    no s_barrier / __syncthreads anywhere; per-wave counted vmcnt is exact.
//  - depth-3 DMA pipeline over 4 LDS buffers (intra-wave reuse: N >= D+1).
//  - block's 4 waves write one contiguous 64B output column (R10's partial-
//    line mistake fixed: lines complete within one CU -> L2 merges).

constexpr int BATCH   = 16;
constexpr int WIN     = 1024;
constexpr int HOP     = 256;
constexpr int NF      = 2048;                       // frames
constexpr int OUT_LEN = (NF - 1) * HOP + WIN;       // 525056
constexpr int GTOT    = OUT_LEN / HOP;              // 2051
constexpr int FT      = 64;                         // g-values per item
constexpr int NT      = (GTOT + FT - 1) / FT;       // 33 tiles (tile 32: g<3)
constexpr int RB      = 16;                         // r-values per block
constexpr int NBUF    = 4;
constexpr int DEPTH   = 3;
constexpr int NBLK    = 512;                        // (half,b,rsp) -> 2/CU

typedef float f4a __attribute__((ext_vector_type(4), aligned(16)));

__global__ __launch_bounds__(256, 2)
void oadd_kernel(const float* __restrict__ x, float* __restrict__ y) {
    // L[s][k][rl][j] = x[b, k*256 + rbase+rl, g0 + j - k]; wave w owns rl=4w..4w+3
    __shared__ float L[NBUF][4][RB][FT];            // 65536 B

    const int tid  = threadIdx.x;
    const int w    = tid >> 6;         // wave 0..3 (owns rows 4w..4w+3)
    const int l    = tid & 63;
    const int bid  = blockIdx.x;
    const int half = bid >> 8;                      // 0: tiles 0..16, 1: 17..32
    const int b    = (bid >> 4) & 15;
    const int rsp  = bid & 15;
    const int rbase = rsp * RB;
    const int tile0 = half ? 17 : 0;
    const int T     = half ? 16 : 17;

    const float* __restrict__ xb = x + (size_t)b * WIN * NF;
    float* __restrict__ yb = y + (size_t)b * OUT_LEN;

    const int sr = l >> 4;             // row within the wave's 4-row slab
    const int c  = l & 15;             // 16B chunk within the 256B row window

    // fill: 4 fire-and-forget 1KB DMAs (one per k), all rows owned by THIS wave
    auto fill = [&](int t, int s) {
        const int tile = tile0 + t;
        const int g0   = tile * FT;
        #pragma unroll
        for (int k = 0; k < 4; ++k) {
            // last tile: clamp window to [NF-FT, NF), remapped in phase2.
            // tile 0, k>0: col<0 dips into previous row's tail (row>=256,
            // in-bounds garbage); masked in phase2.
            const int col0 = (tile == NT - 1) ? (NF - FT) : (g0 - k);
            const float* src = xb + (size_t)(k * HOP + rbase + w * 4 + sr) * NF
                                  + col0 + c * 4;
            __builtin_amdgcn_global_load_lds(
                (const __attribute__((address_space(1))) unsigned int*)src,
                (__attribute__((address_space(3))) unsigned int*)&L[s][k][w * 4][0],
                16, 0, 0);
        }
    };

    // phase2: k-sum + transpose-out, intra-wave only.
    // bank = g%32 -> 2 lanes/bank (free). Store: 16B/lane completing a
    // 64B column with the sibling waves of this block.
    auto phase2 = [&](int t, int s) {
        const int tile = tile0 + t;
        const int g0   = tile * FT;
        if (tile == 0) {
            f4a v;
            #pragma unroll
            for (int m = 0; m < 4; ++m) {
                const int rl = w * 4 + m;
                float a = L[s][0][rl][l];
                if (l >= 1) a += L[s][1][rl][l];
                if (l >= 2) a += L[s][2][rl][l];
                if (l >= 3) a += L[s][3][rl][l];
                v[m] = a;
            }
            *reinterpret_cast<f4a*>(&yb[(size_t)(g0 + l) * HOP + rbase + w * 4]) = v;
        } else if (tile == NT - 1) {
            // valid g only for l<3; window [NF-FT,NF): f = g0+l-k -> idx FT-k+l
            if (l < 3) {
                f4a v;
                #pragma unroll
                for (int m = 0; m < 4; ++m) {
                    const int rl = w * 4 + m;
                    float a = 0.f;
                    #pragma unroll
                    for (int k = 1; k < 4; ++k)
                        if (k > l) a += L[s][k][rl][FT - k + l];
                    v[m] = a;
                }
                *reinterpret_cast<f4a*>(&yb[(size_t)(g0 + l) * HOP + rbase + w * 4]) = v;
            }
        } else {
            f4a v;
            #pragma unroll
            for (int m = 0; m < 4; ++m) {
                const int rl = w * 4 + m;
                v[m] = (L[s][0][rl][l] + L[s][1][rl][l])
                     + (L[s][2][rl][l] + L[s][3][rl][l]);
            }
            *reinterpret_cast<f4a*>(&yb[(size_t)(g0 + l) * HOP + rbase + w * 4]) = v;
        }
    };

    // ---- depth-3 per-wave pipeline, no barriers ----
    fill(0, 0); fill(1, 1); fill(2, 2);
    for (int t = 0; t < T; ++t) {
        if (t + DEPTH < T) fill(t + DEPTH, (t + DEPTH) & 3);
        // per-wave op stream/item: 4 DMAs (+1 store). Keeping <=12 outstanding
        // guarantees item t's 4 DMAs retired (12 = items t+1..t+3 DMAs;
        // interleaved older stores make this conservative, never unsafe).
        if (t + DEPTH < T)  asm volatile("s_waitcnt vmcnt(12)" ::: "memory");
        else if (t + 2 < T) asm volatile("s_waitcnt vmcnt(8)"  ::: "memory");
        else if (t + 1 < T) asm volatile("s_waitcnt vmcnt(4)"  ::: "memory");
        else                asm volatile("s_waitcnt vmcnt(0)"  ::: "memory");
        phase2(t, t & 3);
    }
}

extern "C" void kernel_launch(void* const* d_in, const int* in_sizes, int n_in,
                              void* d_out, int out_size, void* d_ws, size_t ws_size,
                              hipStream_t stream) {
    const float* x = (const float*)d_in[0];
    float* y = (float*)d_out;
    oadd_kernel<<<dim3(NBLK), 256, 0, stream>>>(x, y);
}